// Round 9
// baseline (807.968 us; speedup 1.0000x reference)
//
#include <hip/hip_runtime.h>
#include <math.h>

#define TOPK 8
#define NCORPUS 200000
#define BROWS 1024
#define CHUNK 1024
#define NCHUNK 196           /* ceil(200000/1024) */
#define NTT 128              /* 8 subs * 16 K-steps (BK=32) */
#define NPART 4              /* per-chunk candidate depth */
#define NEGINF (-3.0e38f)

typedef __attribute__((ext_vector_type(8))) short bf16x8;
typedef __attribute__((ext_vector_type(4))) float f32x4;

__device__ __forceinline__ float wave_sum_f32(float v) {
#pragma unroll
  for (int m = 32; m >= 1; m >>= 1) v += __shfl_xor(v, m, 64);
  return v;
}
__device__ __forceinline__ double wave_sum_f64(double v) {
#pragma unroll
  for (int m = 32; m >= 1; m >>= 1) v += __shfl_xor(v, m, 64);
  return v;
}
__device__ __forceinline__ unsigned short f2bf(float f) {
  unsigned int u = __float_as_uint(f);
  unsigned int r = (u + 0x7fffu + ((u >> 16) & 1u)) >> 16;
  return (unsigned short)r;
}
__device__ __forceinline__ void gload16(const void* g, void* l) {
  __builtin_amdgcn_global_load_lds(
      (const __attribute__((address_space(1))) unsigned int*)g,
      (__attribute__((address_space(3))) unsigned int*)l, 16, 0, 0);
}
// 4-deep sorted-desc insert on tagged floats (max/min only)
__device__ __forceinline__ void kins4f(float (&S)[4], float v) {
#pragma unroll
  for (int p = 0; p < 4; ++p) {
    float mx = fmaxf(S[p], v);
    v = fminf(S[p], v);
    S[p] = mx;
  }
}
// merge two sorted-desc-4 float lists -> top-4 sorted desc (max/min network)
__device__ __forceinline__ void pmerge4f(float (&a)[4], const float (&b)[4]) {
  float c0 = fmaxf(a[0], b[3]), c1 = fmaxf(a[1], b[2]);
  float c2 = fmaxf(a[2], b[1]), c3 = fmaxf(a[3], b[0]);
  float t;
  t = fmaxf(c0, c2); c2 = fminf(c0, c2); c0 = t;
  t = fmaxf(c1, c3); c3 = fminf(c1, c3); c1 = t;
  t = fmaxf(c0, c1); c1 = fminf(c0, c1); c0 = t;
  t = fmaxf(c2, c3); c3 = fminf(c2, c3); c2 = t;
  a[0] = c0; a[1] = c1; a[2] = c2; a[3] = c3;
}

// ---------------- q encode (f64 internally) + bf16 pack ----------------
__global__ void qenc_kernel(const float* __restrict__ patient, const float* __restrict__ Wpe,
                            const float* __restrict__ bpe, double* __restrict__ q64,
                            unsigned short* __restrict__ Qpk) {
  int b = blockIdx.x, tid = threadIdx.x;
  __shared__ float ps[66];
  __shared__ double red[4];
  __shared__ double s_den;
  if (tid < 66) ps[tid] = patient[b * 66 + tid];
  __syncthreads();
  double v0 = (double)bpe[tid];
  double v1 = (double)bpe[tid + 256];
  for (int k = 0; k < 66; ++k) {
    double p = (double)ps[k];
    v0 += p * (double)Wpe[k * 512 + tid];
    v1 += p * (double)Wpe[k * 512 + tid + 256];
  }
  double ss = wave_sum_f64(v0 * v0 + v1 * v1);
  if ((tid & 63) == 0) red[tid >> 6] = ss;
  __syncthreads();
  if (tid == 0) s_den = fmax(sqrt(red[0] + red[1] + red[2] + red[3]), 1e-12);
  __syncthreads();
  double den = s_den;
  double o0 = v0 / den, o1 = v1 / den;
  q64[(size_t)b * 512 + tid] = o0;
  q64[(size_t)b * 512 + tid + 256] = o1;
  Qpk[(size_t)b * 512 + tid] = f2bf((float)o0);
  Qpk[(size_t)b * 512 + tid + 256] = f2bf((float)o1);
}

// ---------------- corpus: normalize + bf16 pack ----------------
__global__ void csplit_kernel(const float* __restrict__ corpus, unsigned short* __restrict__ Cpk) {
  int wid = threadIdx.x >> 6, lane = threadIdx.x & 63;
  int row = blockIdx.x * 4 + wid;
  if (row >= NCORPUS) return;
  const float4* p = (const float4*)(corpus + (size_t)row * 512);
  float4 a = p[lane * 2], b = p[lane * 2 + 1];
  float s = a.x * a.x + a.y * a.y + a.z * a.z + a.w * a.w +
            b.x * b.x + b.y * b.y + b.z * b.z + b.w * b.w;
  s = wave_sum_f32(s);
  float inv = 1.0f / fmaxf(sqrtf(s), 1e-12f);
  union { unsigned short us[8]; uint4 v; } pk;
  pk.us[0] = f2bf(a.x * inv); pk.us[1] = f2bf(a.y * inv);
  pk.us[2] = f2bf(a.z * inv); pk.us[3] = f2bf(a.w * inv);
  pk.us[4] = f2bf(b.x * inv); pk.us[5] = f2bf(b.y * inv);
  pk.us[6] = f2bf(b.z * inv); pk.us[7] = f2bf(b.w * inv);
  *(uint4*)(Cpk + (size_t)row * 512 + lane * 8) = pk.v;
}

// fold one sub's acc into tagged-float top-4 lists
template <bool CHECK>
__device__ __forceinline__ void fold_sub(f32x4 (&acc)[4][4], float (&lk)[4][4],
                                         int tagbase, int rb2) {
#pragma unroll
  for (int m = 0; m < 4; ++m)
#pragma unroll
    for (int j = 0; j < 4; ++j) {
      int mj = m * 16 + j;
      unsigned tg = (unsigned)(tagbase - mj);
      bool ok = true;
      if (CHECK) ok = (rb2 + mj) < NCORPUS;
#pragma unroll
      for (int n = 0; n < 4; ++n) {
        unsigned bb = (__float_as_uint(acc[m][n][j]) & 0xFFFFFC00u) | tg;
        float tf = __uint_as_float(bb);
        if (CHECK) tf = ok ? tf : NEGINF;
        kins4f(lk[n], tf);
      }
    }
}

// ---------------- sim^T GEMM via bf16 MFMA + tagged-float top-4 ----------------
// M = corpus rows (chunk of 1024, 8 subs of 128), N = q rows (tile of 128).
// BK=32, 32 KiB LDS -> 4 blocks/CU. Counted-vmcnt pipeline.
__global__ __launch_bounds__(256, 4) void sim_topk_mfma(
    const unsigned short* __restrict__ Qpk, const unsigned short* __restrict__ Cpk,
    unsigned int* __restrict__ part_k) {
  __shared__ __align__(16) unsigned short smem[2][8192];  // [buf][A 4096 | B 4096] ush = 32 KiB

  int tid = threadIdx.x;
  int lane = tid & 63, wid = tid >> 6;
  int wr = wid >> 1, wc = wid & 1;
  // bijective XCD swizzle: blocks sharing a chunk land on one XCD
  int g = (blockIdx.x & 7) * NCHUNK + (blockIdx.x >> 3);
  int chunk = g >> 3, mt = g & 7;
  int m0 = mt * 128;
  int rbase = chunk * CHUNK;
  bool lastChunk = (rbase + CHUNK) > NCORPUS;

  // staging: thread owns 16B granules G0=tid, G1=tid+256 of each 8 KB half-tile.
  // granule G -> (row = G>>2, gcol = G&3); swizzle f(row) = (row&3)^((row>>2)&3)
  // LDS dest linear (G*16 B); global source column pre-swizzled (rule #21).
  int G0 = tid, G1 = tid + 256;
  int r0 = G0 >> 2, r1 = G1 >> 2;
  int sc0 = (((G0 & 3) ^ (r0 & 3) ^ ((r0 >> 2) & 3)) << 3);  // ush offset in 32-ush row
  int sc1 = (((G1 & 3) ^ (r1 & 3) ^ ((r1 >> 2) & 3)) << 3);

  // fragment ds_read offsets (swizzled), ush units; row stride 32 ush = 64 B
  int l15 = lane & 15, l4 = lane >> 4;
  int aoff[4], boff[4];
#pragma unroll
  for (int q = 0; q < 4; ++q) {
    int ar = wr * 64 + q * 16 + l15;
    aoff[q] = ar * 32 + ((l4 ^ (ar & 3) ^ ((ar >> 2) & 3)) << 3);
    int br = wc * 64 + q * 16 + l15;
    boff[q] = 4096 + br * 32 + ((l4 ^ (br & 3) ^ ((br >> 2) & 3)) << 3);
  }

  float lk[4][NPART];  // per-q-col tagged-float top-4, sorted desc
#pragma unroll
  for (int n = 0; n < 4; ++n)
#pragma unroll
    for (int p = 0; p < NPART; ++p) lk[n][p] = NEGINF;

  f32x4 zero = {0.f, 0.f, 0.f, 0.f};
  f32x4 acc[4][4];
#pragma unroll
  for (int m = 0; m < 4; ++m)
#pragma unroll
    for (int n = 0; n < 4; ++n) acc[m][n] = zero;

  auto stageA = [&](int t, unsigned short* dst) {
    int sub = t >> 4, kt = t & 15;
    int rb = rbase + sub * 128;
    int k0 = kt * 32;
    int cr0 = rb + r0; if (cr0 > NCORPUS - 1) cr0 = NCORPUS - 1;
    int cr1 = rb + r1; if (cr1 > NCORPUS - 1) cr1 = NCORPUS - 1;
    gload16(Cpk + (size_t)cr0 * 512 + k0 + sc0, dst + G0 * 8);
    gload16(Cpk + (size_t)cr1 * 512 + k0 + sc1, dst + G1 * 8);
  };
  auto stageB = [&](int t, unsigned short* dst) {
    int k0 = (t & 15) * 32;
    gload16(Qpk + (size_t)(m0 + r0) * 512 + k0 + sc0, dst + 4096 + G0 * 8);
    gload16(Qpk + (size_t)(m0 + r1) * 512 + k0 + sc1, dst + 4096 + G1 * 8);
  };

  // prologue: stage tile 0 (4 loads outstanding)
  stageA(0, smem[0]);
  stageB(0, smem[0]);

  for (int t = 0; t < NTT; ++t) {
    int t1 = t + 1;
    if (t1 < NTT) {
      unsigned short* nb = smem[t1 & 1];
      stageA(t1, nb);
      stageB(t1, nb);
      // wait for stage(t) only; stage(t+1)'s 4 loads stay in flight across the barrier
      asm volatile("s_waitcnt vmcnt(4)" ::: "memory");
    } else {
      asm volatile("s_waitcnt vmcnt(0)" ::: "memory");
    }
    __builtin_amdgcn_s_barrier();   // buf[t] valid for all waves
    const unsigned short* cb = smem[t & 1];
    bf16x8 a[4], b[4];
#pragma unroll
    for (int m = 0; m < 4; ++m) a[m] = *(const bf16x8*)(cb + aoff[m]);
#pragma unroll
    for (int n = 0; n < 4; ++n) b[n] = *(const bf16x8*)(cb + boff[n]);
#pragma unroll
    for (int m = 0; m < 4; ++m)
#pragma unroll
      for (int n = 0; n < 4; ++n)
        acc[m][n] = __builtin_amdgcn_mfma_f32_16x16x32_bf16(a[m], b[n], acc[m][n], 0, 0, 0);
    if ((t & 15) == 15) {  // sub complete: fold acc into tagged-float top-4 lists
      int sub = t >> 4;
      int cellbase = sub * 128 + wr * 64 + l4 * 4;
      int rb2 = rbase + cellbase;
      int tagbase = 1023 - cellbase;
      if (lastChunk) fold_sub<true>(acc, lk, tagbase, rb2);
      else fold_sub<false>(acc, lk, tagbase, rb2);
#pragma unroll
      for (int m = 0; m < 4; ++m)
#pragma unroll
        for (int n = 0; n < 4; ++n) acc[m][n] = zero;
    }
    __builtin_amdgcn_s_barrier();   // all reads of buf[t] done before stage(t+2) overwrites it
  }

  // ---- block-end merge: per q-col partial lists -> chunk top-4 ----
  // within-wave: merge across l4 groups (xor 16, then 32)
#pragma unroll
  for (int rnd = 0; rnd < 2; ++rnd) {
    int msk = 16 << rnd;
#pragma unroll
    for (int n = 0; n < 4; ++n) {
      float ov[NPART];
#pragma unroll
      for (int p = 0; p < NPART; ++p) ov[p] = __shfl_xor(lk[n][p], msk, 64);
      pmerge4f(lk[n], ov);
    }
  }
  // cross-wave (wr=1 -> LDS -> wr=0)
  float* fb = (float*)&smem[0][0];  // [128][4] tagged floats (2 KB)
  if (wr == 1 && l4 == 0) {
#pragma unroll
    for (int n = 0; n < 4; ++n) {
      int col = wc * 64 + n * 16 + l15;
#pragma unroll
      for (int p = 0; p < NPART; ++p) fb[col * 4 + p] = lk[n][p];
    }
  }
  __syncthreads();
  if (wr == 0 && l4 == 0) {
#pragma unroll
    for (int n = 0; n < 4; ++n) {
      int col = wc * 64 + n * 16 + l15;
      float ov[NPART];
#pragma unroll
      for (int p = 0; p < NPART; ++p) ov[p] = fb[col * 4 + p];
      pmerge4f(lk[n], ov);
      size_t base = ((size_t)(m0 + col) * NCHUNK + chunk) * NPART;
#pragma unroll
      for (int p = 0; p < NPART; ++p) {
        unsigned bits = __float_as_uint(lk[n][p]);
        unsigned tag = bits & 0x3FFu;
        unsigned flip = bits ^ ((unsigned)((int)bits >> 31) | 0x80000000u);
        part_k[base + p] = (flip & 0xFFFFFC00u) | tag;  // 22-bit value | 10-bit comp row
      }
    }
  }
}

// ---------------- merge partials (wave-parallel, exact) + f64 refine + final top-8 ----------------
__global__ __launch_bounds__(256, 2) void merge_refine_kernel(
    const unsigned int* __restrict__ part_k,
    const double* __restrict__ q64, const float* __restrict__ corpus,
    float* __restrict__ out_scores, float* __restrict__ out_idxf, int* __restrict__ topidx) {
  int wv = threadIdx.x >> 6, lane = threadIdx.x & 63;
  int row = blockIdx.x * 4 + wv;
  if (row >= BROWS) return;

  unsigned tk[16]; int tm[16];
#pragma unroll
  for (int p = 0; p < 16; ++p) { tk[p] = 0u; tm[p] = 0; }
  const unsigned* base = part_k + (size_t)row * (NCHUNK * NPART);
  for (int e = lane; e < NCHUNK * NPART; e += 64) {  // coalesced
    unsigned k = base[e];
    if (k > tk[15]) {
      unsigned kv = k; int mv = e;
#pragma unroll
      for (int p = 0; p < 16; ++p) {
        bool gt = kv > tk[p];
        unsigned ts = tk[p]; int ti = tm[p];
        tk[p] = gt ? kv : ts; tm[p] = gt ? mv : ti;
        kv = gt ? ts : kv;    mv = gt ? ti : mv;
      }
    }
  }
  // exact tree merge across 64 lanes (key + meta pairs)
#pragma unroll
  for (int r = 0; r < 6; ++r) {
    unsigned ov[16]; int om[16];
#pragma unroll
    for (int p = 0; p < 16; ++p) {
      ov[p] = __shfl_xor(tk[p], 1 << r, 64);
      om[p] = __shfl_xor(tm[p], 1 << r, 64);
    }
    unsigned cv[16]; int cm[16];
#pragma unroll
    for (int i = 0; i < 16; ++i) {
      bool t = tk[i] >= ov[15 - i];
      cv[i] = t ? tk[i] : ov[15 - i];
      cm[i] = t ? tm[i] : om[15 - i];
    }
#pragma unroll
    for (int s = 8; s >= 1; s >>= 1)
#pragma unroll
      for (int bb = 0; bb < 16; bb += 2 * s)
#pragma unroll
        for (int o = 0; o < s; ++o) {
          int x = bb + o, y = bb + o + s;
          bool t = cv[x] >= cv[y];
          unsigned hv = t ? cv[x] : cv[y]; unsigned lv = t ? cv[y] : cv[x];
          int hm = t ? cm[x] : cm[y];      int lm = t ? cm[y] : cm[x];
          cv[x] = hv; cm[x] = hm; cv[y] = lv; cm[y] = lm;
        }
#pragma unroll
    for (int i = 0; i < 16; ++i) { tk[i] = cv[i]; tm[i] = cm[i]; }
  }
  int cidx[16];
#pragma unroll
  for (int c = 0; c < 16; ++c) {
    int ic = ((tm[c] >> 2) << 10) + 1023 - (int)(tk[c] & 0x3FFu);
    if (ic > NCORPUS - 1) ic = NCORPUS - 1;
    if (ic < 0) ic = 0;
    cidx[c] = ic;
  }
  // refine all 16 candidates in f64 (wave-parallel dot)
  double qv[8];
  const double* qrow = q64 + (size_t)row * 512;
#pragma unroll
  for (int t = 0; t < 8; ++t) qv[t] = qrow[lane * 8 + t];
  double rs[16];
#pragma unroll
  for (int c = 0; c < 16; ++c) {
    const float* crow = corpus + (size_t)cidx[c] * 512 + lane * 8;
    double qd = 0.0, cd = 0.0;
#pragma unroll
    for (int t = 0; t < 8; ++t) {
      double x = (double)crow[t];
      cd += x * x;
      qd += qv[t] * x;
    }
    qd = wave_sum_f64(qd);
    cd = wave_sum_f64(cd);
    rs[c] = qd / fmax(sqrt(cd), 1e-12);
  }
  if (lane == 0) {
    for (int o = 0; o < TOPK; ++o) {
      double bsc = -1e300;
      int bid2 = 0x7fffffff, bc = -1;
#pragma unroll
      for (int c = 0; c < 16; ++c) {
        bool better = (rs[c] > bsc) || (rs[c] == bsc && cidx[c] < bid2);
        if (better) { bsc = rs[c]; bid2 = cidx[c]; bc = c; }
      }
      out_scores[row * 8 + o] = (float)bsc;
      out_idxf[row * 8 + o] = (float)bid2;
      topidx[row * 8 + o] = bid2;
#pragma unroll
      for (int c = 0; c < 16; ++c)
        if (c == bc) rs[c] = -1e300;
    }
  }
}

// ---------------- fused treatment/confounder encoders + propensity head ----------------
__global__ void tcenc_prop_kernel(const float* __restrict__ treatment, const float* __restrict__ conf,
                                  const float* __restrict__ Wte, const float* __restrict__ bte,
                                  const float* __restrict__ Wce, const float* __restrict__ bce,
                                  const float* __restrict__ Wp1, const float* __restrict__ bp1,
                                  const float* __restrict__ Wp2, const float* __restrict__ bp2,
                                  float* __restrict__ combined, float* __restrict__ out_prop) {
  int b = blockIdx.x, tid = threadIdx.x;
  __shared__ float cs[64];
  __shared__ float red0[4], red1[4];
  if (tid < 64) cs[tid] = conf[b * 64 + tid];
  __syncthreads();
  float t0 = treatment[b * 2], t1 = treatment[b * 2 + 1];
  float l0 = 0.f, l1 = 0.f;
#pragma unroll
  for (int rep = 0; rep < 2; ++rep) {
    int h = tid + rep * 256;
    float te = fmaf(t0, Wte[h], fmaf(t1, Wte[512 + h], bte[h]));
    combined[(size_t)b * 1536 + h] = te;
    float ce = bce[h];
    float pv = bp1[h];
    for (int k = 0; k < 64; ++k) {
      float c = cs[k];
      ce = fmaf(c, Wce[k * 512 + h], ce);
      pv = fmaf(c, Wp1[k * 512 + h], pv);
    }
    combined[(size_t)b * 1536 + 512 + h] = ce;
    pv = fmaxf(pv, 0.f);
    l0 = fmaf(pv, Wp2[h * 2], l0);
    l1 = fmaf(pv, Wp2[h * 2 + 1], l1);
  }
  l0 = wave_sum_f32(l0);
  l1 = wave_sum_f32(l1);
  int wv = tid >> 6, lane = tid & 63;
  if (lane == 0) { red0[wv] = l0; red1[wv] = l1; }
  __syncthreads();
  if (tid == 0) {
    float a = red0[0] + red0[1] + red0[2] + red0[3] + bp2[0];
    float c2 = red1[0] + red1[1] + red1[2] + red1[3] + bp2[1];
    float m = fmaxf(a, c2);
    float e0 = expf(a - m), e1 = expf(c2 - m);
    float inv = 1.f / (e0 + e1);
    out_prop[b * 2] = e0 * inv;
    out_prop[b * 2 + 1] = e1 * inv;
  }
}

// ---------------- generic 16x64 tiled GEMM, single-barrier dbuf (opt. gather-A, opt. relu) ----------------
template <bool GATHER, bool RELU>
__global__ __launch_bounds__(256, 2) void gemm_k_kernel(
    const float* __restrict__ A, int lda, const float* __restrict__ W, int ldw,
    const float* __restrict__ bias, float* __restrict__ C, int ldc, int K,
    const int* __restrict__ gidx, const float* __restrict__ corpus) {
  __shared__ float As[2][32 * 17];   // [kk][row] transposed, pitch 17
  __shared__ float Bs[2][32 * 68];
  __shared__ int gi[128];
  int tid = threadIdx.x;
  int m0 = blockIdx.y * 16, n0 = blockIdx.x * 64;
  int tr = tid >> 4, tc = tid & 15;   // output: row tr (0..15), col group tc
  int bn = (tid & 15) * 4, bk = tid >> 4;
  if (GATHER) {
    if (tid < 128) gi[tid] = gidx[m0 * 8 + tid];
    __syncthreads();
  }
  auto stage = [&](int kt, int buf) {
    int k0 = kt * 32;
    if (tid < 128) {
      int row = tid & 15, f4 = tid >> 4;  // f4 0..7
      int kk = k0 + f4 * 4;
      const float* src;
      if (GATHER) {
        int r = gi[row * 8 + (kk >> 9)];
        src = corpus + (size_t)r * 512 + (kk & 511);
      } else {
        src = A + (size_t)(m0 + row) * lda + kk;
      }
      float4 v = *(const float4*)src;
      float* d = As[buf] + (f4 * 4) * 17 + row;
      d[0] = v.x; d[17] = v.y; d[34] = v.z; d[51] = v.w;
    }
#pragma unroll
    for (int r = 0; r < 2; ++r) {
      int kk = bk + r * 16;
      float4 v = *(const float4*)(W + (size_t)(k0 + kk) * ldw + n0 + bn);
      *(float4*)(Bs[buf] + kk * 68 + bn) = v;
    }
  };
  float acc[4] = {0.f, 0.f, 0.f, 0.f};
  int nk = K >> 5;
  stage(0, 0);
  __syncthreads();
  for (int kt = 0; kt < nk; ++kt) {
    int cur = kt & 1;
    if (kt + 1 < nk) stage(kt + 1, cur ^ 1);
    const float* as = As[cur];
    const float* bs = Bs[cur];
#pragma unroll
    for (int k = 0; k < 32; ++k) {
      float a0 = as[k * 17 + tr];
      float4 b4 = *(const float4*)(bs + k * 68 + tc * 4);
      acc[0] = fmaf(a0, b4.x, acc[0]);
      acc[1] = fmaf(a0, b4.y, acc[1]);
      acc[2] = fmaf(a0, b4.z, acc[2]);
      acc[3] = fmaf(a0, b4.w, acc[3]);
    }
    __syncthreads();
  }
  int m = m0 + tr;
#pragma unroll
  for (int j = 0; j < 4; ++j) {
    int n = n0 + tc * 4 + j;
    float v = acc[j] + bias[n];
    if (RELU) v = fmaxf(v, 0.f);
    C[(size_t)m * ldc + n] = v;
  }
}

// ---------------- outcome head (N=1) ----------------
__global__ void outcome_kernel(const float* __restrict__ h2, const float* __restrict__ Wo3,
                               const float* __restrict__ bo3, float* __restrict__ out) {
  int wv = threadIdx.x >> 6, lane = threadIdx.x & 63;
  int row = blockIdx.x * 4 + wv;
  if (row >= BROWS) return;
  float4 a = ((const float4*)(h2 + (size_t)row * 256))[lane];
  float4 w = ((const float4*)Wo3)[lane];
  float s = a.x * w.x + a.y * w.y + a.z * w.z + a.w * w.w;
  s = wave_sum_f32(s);
  if (lane == 0) out[row] = s + bo3[0];
}

extern "C" void kernel_launch(void* const* d_in, const int* in_sizes, int n_in,
                              void* d_out, int out_size, void* d_ws, size_t ws_size,
                              hipStream_t stream) {
  const float* treatment = (const float*)d_in[0];
  const float* conf = (const float*)d_in[1];
  const float* patient = (const float*)d_in[2];
  const float* corpus = (const float*)d_in[3];
  const float* Wpe = (const float*)d_in[4];
  const float* bpe = (const float*)d_in[5];
  const float* Wte = (const float*)d_in[6];
  const float* bte = (const float*)d_in[7];
  const float* Wce = (const float*)d_in[8];
  const float* bce = (const float*)d_in[9];
  const float* Wre = (const float*)d_in[10];
  const float* bre = (const float*)d_in[11];
  const float* Wo1 = (const float*)d_in[12];
  const float* bo1 = (const float*)d_in[13];
  const float* Wo2 = (const float*)d_in[14];
  const float* bo2 = (const float*)d_in[15];
  const float* Wo3 = (const float*)d_in[16];
  const float* bo3 = (const float*)d_in[17];
  const float* Wp1 = (const float*)d_in[18];
  const float* bp1 = (const float*)d_in[19];
  const float* Wp2 = (const float*)d_in[20];
  const float* bp2 = (const float*)d_in[21];

  float* out = (float*)d_out;
  float* out_outcome = out;                       // [1024]
  float* out_scores = out + 1024;                 // [1024*8]
  float* out_idxf = out + 1024 + 8192;            // [1024*8] (ints as float)
  float* out_prop = out + 1024 + 8192 + 8192;     // [1024*2]

  char* ws = (char*)d_ws;
  size_t off = 0;
  auto carve = [&](size_t bytes) {
    void* p = ws + off;
    off = (off + bytes + 255) & ~(size_t)255;
    return p;
  };
  double* q64 = (double*)carve((size_t)1024 * 512 * 8);
  unsigned short* Qpk = (unsigned short*)carve((size_t)1024 * 512 * 2);
  unsigned short* Cpk = (unsigned short*)carve((size_t)NCORPUS * 512 * 2);
  unsigned int* part_k = (unsigned int*)carve((size_t)1024 * NCHUNK * NPART * 4);
  int* topidx = (int*)carve((size_t)1024 * 8 * 4);
  float* combined = (float*)carve((size_t)1024 * 1536 * 4);
  float* h1 = (float*)carve((size_t)1024 * 512 * 4);
  float* h2 = (float*)carve((size_t)1024 * 256 * 4);

  csplit_kernel<<<dim3(50000), dim3(256), 0, stream>>>(corpus, Cpk);
  qenc_kernel<<<dim3(1024), dim3(256), 0, stream>>>(patient, Wpe, bpe, q64, Qpk);
  sim_topk_mfma<<<dim3(8 * NCHUNK), dim3(256), 0, stream>>>(Qpk, Cpk, part_k);
  merge_refine_kernel<<<dim3(256), dim3(256), 0, stream>>>(part_k, q64, corpus,
                                                           out_scores, out_idxf, topidx);
  tcenc_prop_kernel<<<dim3(1024), dim3(256), 0, stream>>>(treatment, conf, Wte, bte, Wce, bce,
                                                          Wp1, bp1, Wp2, bp2, combined, out_prop);
  gemm_k_kernel<true, false><<<dim3(8, 64), dim3(256), 0, stream>>>(
      (const float*)nullptr, 0, Wre, 512, bre, combined + 1024, 1536, 4096, topidx, corpus);
  gemm_k_kernel<false, true><<<dim3(8, 64), dim3(256), 0, stream>>>(
      combined, 1536, Wo1, 512, bo1, h1, 512, 1536, (const int*)nullptr, (const float*)nullptr);
  gemm_k_kernel<false, true><<<dim3(4, 64), dim3(256), 0, stream>>>(
      h1, 512, Wo2, 256, bo2, h2, 256, 512, (const int*)nullptr, (const float*)nullptr);
  outcome_kernel<<<dim3(256), dim3(256), 0, stream>>>(h2, Wo3, bo3, out_outcome);
}

// Round 10
// 769.420 us; speedup vs baseline: 1.0501x; 1.0501x over previous
//
#include <hip/hip_runtime.h>
#include <math.h>

#define TOPK 8
#define NCORPUS 200000
#define BROWS 1024
#define CHUNK 1024
#define NCHUNK 196           /* ceil(200000/1024) */
#define NQT 16               /* q tiles of 64 */
#define NT 64                /* 8 subs * 8 K-steps (BK=64) */
#define NPART 4              /* per-chunk candidate depth */
#define NEGINF (-3.0e38f)

typedef __attribute__((ext_vector_type(8))) short bf16x8;
typedef __attribute__((ext_vector_type(4))) float f32x4;

__device__ __forceinline__ float wave_sum_f32(float v) {
#pragma unroll
  for (int m = 32; m >= 1; m >>= 1) v += __shfl_xor(v, m, 64);
  return v;
}
__device__ __forceinline__ double wave_sum_f64(double v) {
#pragma unroll
  for (int m = 32; m >= 1; m >>= 1) v += __shfl_xor(v, m, 64);
  return v;
}
__device__ __forceinline__ unsigned short f2bf(float f) {
  unsigned int u = __float_as_uint(f);
  unsigned int r = (u + 0x7fffu + ((u >> 16) & 1u)) >> 16;
  return (unsigned short)r;
}
__device__ __forceinline__ void gload16(const void* g, void* l) {
  __builtin_amdgcn_global_load_lds(
      (const __attribute__((address_space(1))) unsigned int*)g,
      (__attribute__((address_space(3))) unsigned int*)l, 16, 0, 0);
}
// 4-deep sorted-desc insert on tagged floats (max/min only)
__device__ __forceinline__ void kins4f(float (&S)[4], float v) {
#pragma unroll
  for (int p = 0; p < 4; ++p) {
    float mx = fmaxf(S[p], v);
    v = fminf(S[p], v);
    S[p] = mx;
  }
}
// merge two sorted-desc-4 float lists -> top-4 sorted desc (max/min network)
__device__ __forceinline__ void pmerge4f(float (&a)[4], const float (&b)[4]) {
  float c0 = fmaxf(a[0], b[3]), c1 = fmaxf(a[1], b[2]);
  float c2 = fmaxf(a[2], b[1]), c3 = fmaxf(a[3], b[0]);
  float t;
  t = fmaxf(c0, c2); c2 = fminf(c0, c2); c0 = t;
  t = fmaxf(c1, c3); c3 = fminf(c1, c3); c1 = t;
  t = fmaxf(c0, c1); c1 = fminf(c0, c1); c0 = t;
  t = fmaxf(c2, c3); c3 = fminf(c2, c3); c2 = t;
  a[0] = c0; a[1] = c1; a[2] = c2; a[3] = c3;
}

// ---------------- q encode (f64 internally) + bf16 pack ----------------
__global__ void qenc_kernel(const float* __restrict__ patient, const float* __restrict__ Wpe,
                            const float* __restrict__ bpe, double* __restrict__ q64,
                            unsigned short* __restrict__ Qpk) {
  int b = blockIdx.x, tid = threadIdx.x;
  __shared__ float ps[66];
  __shared__ double red[4];
  __shared__ double s_den;
  if (tid < 66) ps[tid] = patient[b * 66 + tid];
  __syncthreads();
  double v0 = (double)bpe[tid];
  double v1 = (double)bpe[tid + 256];
  for (int k = 0; k < 66; ++k) {
    double p = (double)ps[k];
    v0 += p * (double)Wpe[k * 512 + tid];
    v1 += p * (double)Wpe[k * 512 + tid + 256];
  }
  double ss = wave_sum_f64(v0 * v0 + v1 * v1);
  if ((tid & 63) == 0) red[tid >> 6] = ss;
  __syncthreads();
  if (tid == 0) s_den = fmax(sqrt(red[0] + red[1] + red[2] + red[3]), 1e-12);
  __syncthreads();
  double den = s_den;
  double o0 = v0 / den, o1 = v1 / den;
  q64[(size_t)b * 512 + tid] = o0;
  q64[(size_t)b * 512 + tid + 256] = o1;
  Qpk[(size_t)b * 512 + tid] = f2bf((float)o0);
  Qpk[(size_t)b * 512 + tid + 256] = f2bf((float)o1);
}

// ---------------- corpus: normalize + bf16 pack ----------------
__global__ void csplit_kernel(const float* __restrict__ corpus, unsigned short* __restrict__ Cpk) {
  int wid = threadIdx.x >> 6, lane = threadIdx.x & 63;
  int row = blockIdx.x * 4 + wid;
  if (row >= NCORPUS) return;
  const float4* p = (const float4*)(corpus + (size_t)row * 512);
  float4 a = p[lane * 2], b = p[lane * 2 + 1];
  float s = a.x * a.x + a.y * a.y + a.z * a.z + a.w * a.w +
            b.x * b.x + b.y * b.y + b.z * b.z + b.w * b.w;
  s = wave_sum_f32(s);
  float inv = 1.0f / fmaxf(sqrtf(s), 1e-12f);
  union { unsigned short us[8]; uint4 v; } pk;
  pk.us[0] = f2bf(a.x * inv); pk.us[1] = f2bf(a.y * inv);
  pk.us[2] = f2bf(a.z * inv); pk.us[3] = f2bf(a.w * inv);
  pk.us[4] = f2bf(b.x * inv); pk.us[5] = f2bf(b.y * inv);
  pk.us[6] = f2bf(b.z * inv); pk.us[7] = f2bf(b.w * inv);
  *(uint4*)(Cpk + (size_t)row * 512 + lane * 8) = pk.v;
}

// fold one sub's acc into tagged-float top-4 lists
template <bool CHECK>
__device__ __forceinline__ void fold_sub(f32x4 (&acc)[4][2], float (&lk)[2][4],
                                         int tagbase, int rb2) {
#pragma unroll
  for (int m = 0; m < 4; ++m)
#pragma unroll
    for (int j = 0; j < 4; ++j) {
      int mj = m * 16 + j;
      unsigned tg = (unsigned)(tagbase - mj);
      bool ok = true;
      if (CHECK) ok = (rb2 + mj) < NCORPUS;
#pragma unroll
      for (int n = 0; n < 2; ++n) {
        unsigned bb = (__float_as_uint(acc[m][n][j]) & 0xFFFFFC00u) | tg;
        float tf = __uint_as_float(bb);
        if (CHECK) tf = ok ? tf : NEGINF;
        kins4f(lk[n], tf);
      }
    }
}

// ---------------- sim^T GEMM via bf16 MFMA + tagged-float top-4 ----------------
// Tile: M(corpus)=128 x N(q)=64, BK=64 (128-B LDS rows, verified-zero-conflict swizzle).
// 48 KiB LDS -> 3 blocks/CU. Counted-vmcnt(6) pipeline.
__global__ __launch_bounds__(256, 2) void sim_topk_mfma(
    const unsigned short* __restrict__ Qpk, const unsigned short* __restrict__ Cpk,
    unsigned int* __restrict__ part_k) {
  __shared__ __align__(16) unsigned short smem[2][12288];  // [buf][A 8192 | B 4096] ush = 48 KiB

  int tid = threadIdx.x;
  int lane = tid & 63, wid = tid >> 6;
  int wr = wid >> 1, wc = wid & 1;
  // bijective XCD swizzle: a chunk's 16 q-tile blocks land on one XCD
  int bid = blockIdx.x;
  int g = (bid & 7) * (NQT * NCHUNK / 8) + (bid >> 3);
  int chunk = g >> 4, qt = g & 15;
  int n0 = qt * 64;
  int rbase = chunk * CHUNK;
  bool lastChunk = (rbase + CHUNK) > NCORPUS;

  // fragment ds_read offsets (swizzled), ush units; row stride 64 ush = 128 B
  int l15 = lane & 15, l4 = lane >> 4;
  int aoff[2][4], boff[2][2];
#pragma unroll
  for (int kk = 0; kk < 2; ++kk) {
#pragma unroll
    for (int m = 0; m < 4; ++m) {
      int ar = wr * 64 + m * 16 + l15;
      aoff[kk][m] = ar * 64 + (((kk * 4 + l4) ^ (ar & 7)) << 3);
    }
#pragma unroll
    for (int n = 0; n < 2; ++n) {
      int br = wc * 32 + n * 16 + l15;
      boff[kk][n] = 8192 + br * 64 + (((kk * 4 + l4) ^ (br & 7)) << 3);
    }
  }

  float lk[2][NPART];  // per-q-col tagged-float top-4, sorted desc
#pragma unroll
  for (int n = 0; n < 2; ++n)
#pragma unroll
    for (int p = 0; p < NPART; ++p) lk[n][p] = NEGINF;

  f32x4 zero = {0.f, 0.f, 0.f, 0.f};
  f32x4 acc[4][2];
#pragma unroll
  for (int m = 0; m < 4; ++m)
#pragma unroll
    for (int n = 0; n < 2; ++n) acc[m][n] = zero;

  // staging: granule G (16 B) -> row r=G>>3, slot gc=G&7; source col pre-swizzled by r&7
  auto stageA = [&](int t, unsigned short* dst) {   // 128 rows, 1024 granules, 4/thread
    int sub = t >> 3, kt = t & 7;
    int rb = rbase + sub * 128;
    int k0 = kt * 64;
#pragma unroll
    for (int i = 0; i < 4; ++i) {
      int G = tid + i * 256;
      int r = G >> 3;
      int sc = ((G ^ r) & 7) << 3;
      int cr = rb + r; if (cr > NCORPUS - 1) cr = NCORPUS - 1;
      gload16(Cpk + (size_t)cr * 512 + k0 + sc, dst + G * 8);
    }
  };
  auto stageB = [&](int t, unsigned short* dst) {   // 64 rows, 512 granules, 2/thread
    int k0 = (t & 7) * 64;
#pragma unroll
    for (int i = 0; i < 2; ++i) {
      int G = tid + i * 256;
      int r = G >> 3;
      int sc = ((G ^ r) & 7) << 3;
      gload16(Qpk + (size_t)(n0 + r) * 512 + k0 + sc, dst + 8192 + G * 8);
    }
  };

  // prologue: stage tile 0 (6 loads outstanding)
  stageA(0, smem[0]);
  stageB(0, smem[0]);

  for (int t = 0; t < NT; ++t) {
    int t1 = t + 1;
    if (t1 < NT) {
      unsigned short* nb = smem[t1 & 1];
      stageA(t1, nb);
      stageB(t1, nb);
      // wait for stage(t) only; stage(t+1)'s 6 loads stay in flight across the barrier
      asm volatile("s_waitcnt vmcnt(6)" ::: "memory");
    } else {
      asm volatile("s_waitcnt vmcnt(0)" ::: "memory");
    }
    __builtin_amdgcn_s_barrier();   // buf[t] valid for all waves
    const unsigned short* cb = smem[t & 1];
#pragma unroll
    for (int kk = 0; kk < 2; ++kk) {
      bf16x8 a[4], b[2];
#pragma unroll
      for (int m = 0; m < 4; ++m) a[m] = *(const bf16x8*)(cb + aoff[kk][m]);
#pragma unroll
      for (int n = 0; n < 2; ++n) b[n] = *(const bf16x8*)(cb + boff[kk][n]);
#pragma unroll
      for (int m = 0; m < 4; ++m)
#pragma unroll
        for (int n = 0; n < 2; ++n)
          acc[m][n] = __builtin_amdgcn_mfma_f32_16x16x32_bf16(a[m], b[n], acc[m][n], 0, 0, 0);
    }
    if ((t & 7) == 7) {  // sub complete: fold acc into tagged-float top-4 lists
      int sub = t >> 3;
      int cellbase = sub * 128 + wr * 64 + l4 * 4;
      int rb2 = rbase + cellbase;
      int tagbase = 1023 - cellbase;
      if (lastChunk) fold_sub<true>(acc, lk, tagbase, rb2);
      else fold_sub<false>(acc, lk, tagbase, rb2);
#pragma unroll
      for (int m = 0; m < 4; ++m)
#pragma unroll
        for (int n = 0; n < 2; ++n) acc[m][n] = zero;
    }
    __builtin_amdgcn_s_barrier();   // all reads of buf[t] done before stage(t+2) overwrites it
  }

  // ---- block-end merge: per q-col partial lists -> chunk top-4 ----
  // within-wave: merge across l4 groups (xor 16, then 32)
#pragma unroll
  for (int rnd = 0; rnd < 2; ++rnd) {
    int msk = 16 << rnd;
#pragma unroll
    for (int n = 0; n < 2; ++n) {
      float ov[NPART];
#pragma unroll
      for (int p = 0; p < NPART; ++p) ov[p] = __shfl_xor(lk[n][p], msk, 64);
      pmerge4f(lk[n], ov);
    }
  }
  // cross-wave (wr=1 -> LDS -> wr=0); cols 0..63
  float* fb = (float*)&smem[0][0];  // [64][4] tagged floats (1 KB)
  if (wr == 1 && l4 == 0) {
#pragma unroll
    for (int n = 0; n < 2; ++n) {
      int col = wc * 32 + n * 16 + l15;
#pragma unroll
      for (int p = 0; p < NPART; ++p) fb[col * 4 + p] = lk[n][p];
    }
  }
  __syncthreads();
  if (wr == 0 && l4 == 0) {
#pragma unroll
    for (int n = 0; n < 2; ++n) {
      int col = wc * 32 + n * 16 + l15;
      float ov[NPART];
#pragma unroll
      for (int p = 0; p < NPART; ++p) ov[p] = fb[col * 4 + p];
      pmerge4f(lk[n], ov);
      size_t base = ((size_t)(n0 + col) * NCHUNK + chunk) * NPART;
#pragma unroll
      for (int p = 0; p < NPART; ++p) {
        unsigned bits = __float_as_uint(lk[n][p]);
        unsigned tag = bits & 0x3FFu;
        unsigned flip = bits ^ ((unsigned)((int)bits >> 31) | 0x80000000u);
        part_k[base + p] = (flip & 0xFFFFFC00u) | tag;  // 22-bit value | 10-bit comp row
      }
    }
  }
}

// ---------------- merge partials (wave-parallel, exact) + f64 refine + final top-8 ----------------
__global__ __launch_bounds__(256, 2) void merge_refine_kernel(
    const unsigned int* __restrict__ part_k,
    const double* __restrict__ q64, const float* __restrict__ corpus,
    float* __restrict__ out_scores, float* __restrict__ out_idxf, int* __restrict__ topidx) {
  int wv = threadIdx.x >> 6, lane = threadIdx.x & 63;
  int row = blockIdx.x * 4 + wv;
  if (row >= BROWS) return;

  unsigned tk[16]; int tm[16];
#pragma unroll
  for (int p = 0; p < 16; ++p) { tk[p] = 0u; tm[p] = 0; }
  const unsigned* base = part_k + (size_t)row * (NCHUNK * NPART);
  for (int e = lane; e < NCHUNK * NPART; e += 64) {  // coalesced
    unsigned k = base[e];
    if (k > tk[15]) {
      unsigned kv = k; int mv = e;
#pragma unroll
      for (int p = 0; p < 16; ++p) {
        bool gt = kv > tk[p];
        unsigned ts = tk[p]; int ti = tm[p];
        tk[p] = gt ? kv : ts; tm[p] = gt ? mv : ti;
        kv = gt ? ts : kv;    mv = gt ? ti : mv;
      }
    }
  }
  // exact tree merge across 64 lanes (key + meta pairs)
#pragma unroll
  for (int r = 0; r < 6; ++r) {
    unsigned ov[16]; int om[16];
#pragma unroll
    for (int p = 0; p < 16; ++p) {
      ov[p] = __shfl_xor(tk[p], 1 << r, 64);
      om[p] = __shfl_xor(tm[p], 1 << r, 64);
    }
    unsigned cv[16]; int cm[16];
#pragma unroll
    for (int i = 0; i < 16; ++i) {
      bool t = tk[i] >= ov[15 - i];
      cv[i] = t ? tk[i] : ov[15 - i];
      cm[i] = t ? tm[i] : om[15 - i];
    }
#pragma unroll
    for (int s = 8; s >= 1; s >>= 1)
#pragma unroll
      for (int bb = 0; bb < 16; bb += 2 * s)
#pragma unroll
        for (int o = 0; o < s; ++o) {
          int x = bb + o, y = bb + o + s;
          bool t = cv[x] >= cv[y];
          unsigned hv = t ? cv[x] : cv[y]; unsigned lv = t ? cv[y] : cv[x];
          int hm = t ? cm[x] : cm[y];      int lm = t ? cm[y] : cm[x];
          cv[x] = hv; cm[x] = hm; cv[y] = lv; cm[y] = lm;
        }
#pragma unroll
    for (int i = 0; i < 16; ++i) { tk[i] = cv[i]; tm[i] = cm[i]; }
  }
  int cidx[16];
#pragma unroll
  for (int c = 0; c < 16; ++c) {
    int ic = ((tm[c] >> 2) << 10) + 1023 - (int)(tk[c] & 0x3FFu);
    if (ic > NCORPUS - 1) ic = NCORPUS - 1;
    if (ic < 0) ic = 0;
    cidx[c] = ic;
  }
  // refine all 16 candidates in f64 (wave-parallel dot)
  double qv[8];
  const double* qrow = q64 + (size_t)row * 512;
#pragma unroll
  for (int t = 0; t < 8; ++t) qv[t] = qrow[lane * 8 + t];
  double rs[16];
#pragma unroll
  for (int c = 0; c < 16; ++c) {
    const float* crow = corpus + (size_t)cidx[c] * 512 + lane * 8;
    double qd = 0.0, cd = 0.0;
#pragma unroll
    for (int t = 0; t < 8; ++t) {
      double x = (double)crow[t];
      cd += x * x;
      qd += qv[t] * x;
    }
    qd = wave_sum_f64(qd);
    cd = wave_sum_f64(cd);
    rs[c] = qd / fmax(sqrt(cd), 1e-12);
  }
  if (lane == 0) {
    for (int o = 0; o < TOPK; ++o) {
      double bsc = -1e300;
      int bid2 = 0x7fffffff, bc = -1;
#pragma unroll
      for (int c = 0; c < 16; ++c) {
        bool better = (rs[c] > bsc) || (rs[c] == bsc && cidx[c] < bid2);
        if (better) { bsc = rs[c]; bid2 = cidx[c]; bc = c; }
      }
      out_scores[row * 8 + o] = (float)bsc;
      out_idxf[row * 8 + o] = (float)bid2;
      topidx[row * 8 + o] = bid2;
#pragma unroll
      for (int c = 0; c < 16; ++c)
        if (c == bc) rs[c] = -1e300;
    }
  }
}

// ---------------- fused treatment/confounder encoders + propensity head ----------------
__global__ void tcenc_prop_kernel(const float* __restrict__ treatment, const float* __restrict__ conf,
                                  const float* __restrict__ Wte, const float* __restrict__ bte,
                                  const float* __restrict__ Wce, const float* __restrict__ bce,
                                  const float* __restrict__ Wp1, const float* __restrict__ bp1,
                                  const float* __restrict__ Wp2, const float* __restrict__ bp2,
                                  float* __restrict__ combined, float* __restrict__ out_prop) {
  int b = blockIdx.x, tid = threadIdx.x;
  __shared__ float cs[64];
  __shared__ float red0[4], red1[4];
  if (tid < 64) cs[tid] = conf[b * 64 + tid];
  __syncthreads();
  float t0 = treatment[b * 2], t1 = treatment[b * 2 + 1];
  float l0 = 0.f, l1 = 0.f;
#pragma unroll
  for (int rep = 0; rep < 2; ++rep) {
    int h = tid + rep * 256;
    float te = fmaf(t0, Wte[h], fmaf(t1, Wte[512 + h], bte[h]));
    combined[(size_t)b * 1536 + h] = te;
    float ce = bce[h];
    float pv = bp1[h];
    for (int k = 0; k < 64; ++k) {
      float c = cs[k];
      ce = fmaf(c, Wce[k * 512 + h], ce);
      pv = fmaf(c, Wp1[k * 512 + h], pv);
    }
    combined[(size_t)b * 1536 + 512 + h] = ce;
    pv = fmaxf(pv, 0.f);
    l0 = fmaf(pv, Wp2[h * 2], l0);
    l1 = fmaf(pv, Wp2[h * 2 + 1], l1);
  }
  l0 = wave_sum_f32(l0);
  l1 = wave_sum_f32(l1);
  int wv = tid >> 6, lane = tid & 63;
  if (lane == 0) { red0[wv] = l0; red1[wv] = l1; }
  __syncthreads();
  if (tid == 0) {
    float a = red0[0] + red0[1] + red0[2] + red0[3] + bp2[0];
    float c2 = red1[0] + red1[1] + red1[2] + red1[3] + bp2[1];
    float m = fmaxf(a, c2);
    float e0 = expf(a - m), e1 = expf(c2 - m);
    float inv = 1.f / (e0 + e1);
    out_prop[b * 2] = e0 * inv;
    out_prop[b * 2 + 1] = e1 * inv;
  }
}

// ---------------- generic 16x64 tiled GEMM, single-barrier dbuf (opt. gather-A, opt. relu) ----------------
template <bool GATHER, bool RELU>
__global__ __launch_bounds__(256, 2) void gemm_k_kernel(
    const float* __restrict__ A, int lda, const float* __restrict__ W, int ldw,
    const float* __restrict__ bias, float* __restrict__ C, int ldc, int K,
    const int* __restrict__ gidx, const float* __restrict__ corpus) {
  __shared__ float As[2][32 * 17];   // [kk][row] transposed, pitch 17
  __shared__ float Bs[2][32 * 68];
  __shared__ int gi[128];
  int tid = threadIdx.x;
  int m0 = blockIdx.y * 16, n0 = blockIdx.x * 64;
  int tr = tid >> 4, tc = tid & 15;   // output: row tr (0..15), col group tc
  int bn = (tid & 15) * 4, bk = tid >> 4;
  if (GATHER) {
    if (tid < 128) gi[tid] = gidx[m0 * 8 + tid];
    __syncthreads();
  }
  auto stage = [&](int kt, int buf) {
    int k0 = kt * 32;
    if (tid < 128) {
      int row = tid & 15, f4 = tid >> 4;  // f4 0..7
      int kk = k0 + f4 * 4;
      const float* src;
      if (GATHER) {
        int r = gi[row * 8 + (kk >> 9)];
        src = corpus + (size_t)r * 512 + (kk & 511);
      } else {
        src = A + (size_t)(m0 + row) * lda + kk;
      }
      float4 v = *(const float4*)src;
      float* d = As[buf] + (f4 * 4) * 17 + row;
      d[0] = v.x; d[17] = v.y; d[34] = v.z; d[51] = v.w;
    }
#pragma unroll
    for (int r = 0; r < 2; ++r) {
      int kk = bk + r * 16;
      float4 v = *(const float4*)(W + (size_t)(k0 + kk) * ldw + n0 + bn);
      *(float4*)(Bs[buf] + kk * 68 + bn) = v;
    }
  };
  float acc[4] = {0.f, 0.f, 0.f, 0.f};
  int nk = K >> 5;
  stage(0, 0);
  __syncthreads();
  for (int kt = 0; kt < nk; ++kt) {
    int cur = kt & 1;
    if (kt + 1 < nk) stage(kt + 1, cur ^ 1);
    const float* as = As[cur];
    const float* bs = Bs[cur];
#pragma unroll
    for (int k = 0; k < 32; ++k) {
      float a0 = as[k * 17 + tr];
      float4 b4 = *(const float4*)(bs + k * 68 + tc * 4);
      acc[0] = fmaf(a0, b4.x, acc[0]);
      acc[1] = fmaf(a0, b4.y, acc[1]);
      acc[2] = fmaf(a0, b4.z, acc[2]);
      acc[3] = fmaf(a0, b4.w, acc[3]);
    }
    __syncthreads();
  }
  int m = m0 + tr;
#pragma unroll
  for (int j = 0; j < 4; ++j) {
    int n = n0 + tc * 4 + j;
    float v = acc[j] + bias[n];
    if (RELU) v = fmaxf(v, 0.f);
    C[(size_t)m * ldc + n] = v;
  }
}

// ---------------- outcome head (N=1) ----------------
__global__ void outcome_kernel(const float* __restrict__ h2, const float* __restrict__ Wo3,
                               const float* __restrict__ bo3, float* __restrict__ out) {
  int wv = threadIdx.x >> 6, lane = threadIdx.x & 63;
  int row = blockIdx.x * 4 + wv;
  if (row >= BROWS) return;
  float4 a = ((const float4*)(h2 + (size_t)row * 256))[lane];
  float4 w = ((const float4*)Wo3)[lane];
  float s = a.x * w.x + a.y * w.y + a.z * w.z + a.w * w.w;
  s = wave_sum_f32(s);
  if (lane == 0) out[row] = s + bo3[0];
}

extern "C" void kernel_launch(void* const* d_in, const int* in_sizes, int n_in,
                              void* d_out, int out_size, void* d_ws, size_t ws_size,
                              hipStream_t stream) {
  const float* treatment = (const float*)d_in[0];
  const float* conf = (const float*)d_in[1];
  const float* patient = (const float*)d_in[2];
  const float* corpus = (const float*)d_in[3];
  const float* Wpe = (const float*)d_in[4];
  const float* bpe = (const float*)d_in[5];
  const float* Wte = (const float*)d_in[6];
  const float* bte = (const float*)d_in[7];
  const float* Wce = (const float*)d_in[8];
  const float* bce = (const float*)d_in[9];
  const float* Wre = (const float*)d_in[10];
  const float* bre = (const float*)d_in[11];
  const float* Wo1 = (const float*)d_in[12];
  const float* bo1 = (const float*)d_in[13];
  const float* Wo2 = (const float*)d_in[14];
  const float* bo2 = (const float*)d_in[15];
  const float* Wo3 = (const float*)d_in[16];
  const float* bo3 = (const float*)d_in[17];
  const float* Wp1 = (const float*)d_in[18];
  const float* bp1 = (const float*)d_in[19];
  const float* Wp2 = (const float*)d_in[20];
  const float* bp2 = (const float*)d_in[21];

  float* out = (float*)d_out;
  float* out_outcome = out;                       // [1024]
  float* out_scores = out + 1024;                 // [1024*8]
  float* out_idxf = out + 1024 + 8192;            // [1024*8] (ints as float)
  float* out_prop = out + 1024 + 8192 + 8192;     // [1024*2]

  char* ws = (char*)d_ws;
  size_t off = 0;
  auto carve = [&](size_t bytes) {
    void* p = ws + off;
    off = (off + bytes + 255) & ~(size_t)255;
    return p;
  };
  double* q64 = (double*)carve((size_t)1024 * 512 * 8);
  unsigned short* Qpk = (unsigned short*)carve((size_t)1024 * 512 * 2);
  unsigned short* Cpk = (unsigned short*)carve((size_t)NCORPUS * 512 * 2);
  unsigned int* part_k = (unsigned int*)carve((size_t)1024 * NCHUNK * NPART * 4);
  int* topidx = (int*)carve((size_t)1024 * 8 * 4);
  float* combined = (float*)carve((size_t)1024 * 1536 * 4);
  float* h1 = (float*)carve((size_t)1024 * 512 * 4);
  float* h2 = (float*)carve((size_t)1024 * 256 * 4);

  csplit_kernel<<<dim3(50000), dim3(256), 0, stream>>>(corpus, Cpk);
  qenc_kernel<<<dim3(1024), dim3(256), 0, stream>>>(patient, Wpe, bpe, q64, Qpk);
  sim_topk_mfma<<<dim3(NQT * NCHUNK), dim3(256), 0, stream>>>(Qpk, Cpk, part_k);
  merge_refine_kernel<<<dim3(256), dim3(256), 0, stream>>>(part_k, q64, corpus,
                                                           out_scores, out_idxf, topidx);
  tcenc_prop_kernel<<<dim3(1024), dim3(256), 0, stream>>>(treatment, conf, Wte, bte, Wce, bce,
                                                          Wp1, bp1, Wp2, bp2, combined, out_prop);
  gemm_k_kernel<true, false><<<dim3(8, 64), dim3(256), 0, stream>>>(
      (const float*)nullptr, 0, Wre, 512, bre, combined + 1024, 1536, 4096, topidx, corpus);
  gemm_k_kernel<false, true><<<dim3(8, 64), dim3(256), 0, stream>>>(
      combined, 1536, Wo1, 512, bo1, h1, 512, 1536, (const int*)nullptr, (const float*)nullptr);
  gemm_k_kernel<false, true><<<dim3(4, 64), dim3(256), 0, stream>>>(
      h1, 512, Wo2, 256, bo2, h2, 256, 512, (const int*)nullptr, (const float*)nullptr);
  outcome_kernel<<<dim3(256), dim3(256), 0, stream>>>(h2, Wo3, bo3, out_outcome);
}

// Round 11
// 725.398 us; speedup vs baseline: 1.1138x; 1.0607x over previous
//
#include <hip/hip_runtime.h>
#include <math.h>

#define TOPK 8
#define NCORPUS 200000
#define BROWS 1024
#define CHUNK 512
#define NCHUNK 391           /* ceil(200000/512) */
#define NT 32                /* 4 subs * 8 K-steps (BK=64) */
#define NPART 4              /* per-chunk candidate depth */
#define NEGINF (-3.0e38f)

typedef __attribute__((ext_vector_type(8))) short bf16x8;
typedef __attribute__((ext_vector_type(4))) float f32x4;

__device__ __forceinline__ float wave_sum_f32(float v) {
#pragma unroll
  for (int m = 32; m >= 1; m >>= 1) v += __shfl_xor(v, m, 64);
  return v;
}
__device__ __forceinline__ double wave_sum_f64(double v) {
#pragma unroll
  for (int m = 32; m >= 1; m >>= 1) v += __shfl_xor(v, m, 64);
  return v;
}
__device__ __forceinline__ unsigned short f2bf(float f) {
  unsigned int u = __float_as_uint(f);
  unsigned int r = (u + 0x7fffu + ((u >> 16) & 1u)) >> 16;
  return (unsigned short)r;
}
__device__ __forceinline__ void gload16(const void* g, void* l) {
  __builtin_amdgcn_global_load_lds(
      (const __attribute__((address_space(1))) unsigned int*)g,
      (__attribute__((address_space(3))) unsigned int*)l, 16, 0, 0);
}
// 4-deep sorted-desc insert on tagged floats (max/min only)
__device__ __forceinline__ void kins4f(float (&S)[4], float v) {
#pragma unroll
  for (int p = 0; p < 4; ++p) {
    float mx = fmaxf(S[p], v);
    v = fminf(S[p], v);
    S[p] = mx;
  }
}
// merge two sorted-desc-4 float lists -> top-4 sorted desc (max/min network)
__device__ __forceinline__ void pmerge4f(float (&a)[4], const float (&b)[4]) {
  float c0 = fmaxf(a[0], b[3]), c1 = fmaxf(a[1], b[2]);
  float c2 = fmaxf(a[2], b[1]), c3 = fmaxf(a[3], b[0]);
  float t;
  t = fmaxf(c0, c2); c2 = fminf(c0, c2); c0 = t;
  t = fmaxf(c1, c3); c3 = fminf(c1, c3); c1 = t;
  t = fmaxf(c0, c1); c1 = fminf(c0, c1); c0 = t;
  t = fmaxf(c2, c3); c3 = fminf(c2, c3); c2 = t;
  a[0] = c0; a[1] = c1; a[2] = c2; a[3] = c3;
}

// ---------------- merged: corpus normalize+pack (blocks 0..49999) | q encode (50000..51023) ----------------
__global__ void prep_kernel(const float* __restrict__ corpus, unsigned short* __restrict__ Cpk,
                            const float* __restrict__ patient, const float* __restrict__ Wpe,
                            const float* __restrict__ bpe, double* __restrict__ q64,
                            unsigned short* __restrict__ Qpk) {
  __shared__ float ps[66];
  __shared__ double red[4];
  __shared__ double s_den;
  int tid = threadIdx.x;
  if (blockIdx.x < 50000) {
    int wid = tid >> 6, lane = tid & 63;
    int row = blockIdx.x * 4 + wid;
    if (row >= NCORPUS) return;
    const float4* p = (const float4*)(corpus + (size_t)row * 512);
    float4 a = p[lane * 2], b = p[lane * 2 + 1];
    float s = a.x * a.x + a.y * a.y + a.z * a.z + a.w * a.w +
              b.x * b.x + b.y * b.y + b.z * b.z + b.w * b.w;
    s = wave_sum_f32(s);
    float inv = 1.0f / fmaxf(sqrtf(s), 1e-12f);
    union { unsigned short us[8]; uint4 v; } pk;
    pk.us[0] = f2bf(a.x * inv); pk.us[1] = f2bf(a.y * inv);
    pk.us[2] = f2bf(a.z * inv); pk.us[3] = f2bf(a.w * inv);
    pk.us[4] = f2bf(b.x * inv); pk.us[5] = f2bf(b.y * inv);
    pk.us[6] = f2bf(b.z * inv); pk.us[7] = f2bf(b.w * inv);
    *(uint4*)(Cpk + (size_t)row * 512 + lane * 8) = pk.v;
  } else {
    int b = blockIdx.x - 50000;
    if (tid < 66) ps[tid] = patient[b * 66 + tid];
    __syncthreads();
    double v0 = (double)bpe[tid];
    double v1 = (double)bpe[tid + 256];
    for (int k = 0; k < 66; ++k) {
      double p = (double)ps[k];
      v0 += p * (double)Wpe[k * 512 + tid];
      v1 += p * (double)Wpe[k * 512 + tid + 256];
    }
    double ss = wave_sum_f64(v0 * v0 + v1 * v1);
    if ((tid & 63) == 0) red[tid >> 6] = ss;
    __syncthreads();
    if (tid == 0) s_den = fmax(sqrt(red[0] + red[1] + red[2] + red[3]), 1e-12);
    __syncthreads();
    double den = s_den;
    double o0 = v0 / den, o1 = v1 / den;
    q64[(size_t)b * 512 + tid] = o0;
    q64[(size_t)b * 512 + tid + 256] = o1;
    Qpk[(size_t)b * 512 + tid] = f2bf((float)o0);
    Qpk[(size_t)b * 512 + tid + 256] = f2bf((float)o1);
  }
}

// fold one sub's acc into tagged-float top-4 lists
template <bool CHECK>
__device__ __forceinline__ void fold_sub(f32x4 (&acc)[4][4], float (&lk)[4][4],
                                         int tagbase, int rb2) {
#pragma unroll
  for (int m = 0; m < 4; ++m)
#pragma unroll
    for (int j = 0; j < 4; ++j) {
      int mj = m * 16 + j;
      unsigned tg = (unsigned)(tagbase - mj);
      bool ok = true;
      if (CHECK) ok = (rb2 + mj) < NCORPUS;
#pragma unroll
      for (int n = 0; n < 4; ++n) {
        unsigned bb = (__float_as_uint(acc[m][n][j]) & 0xFFFFFC00u) | tg;
        float tf = __uint_as_float(bb);
        if (CHECK) tf = ok ? tf : NEGINF;
        kins4f(lk[n], tf);
      }
    }
}

// ---------------- sim^T GEMM via bf16 MFMA + tagged-float top-4 ----------------
// M = corpus rows (chunk of 512, 4 subs of 128), N = q rows (tile of 128).
// BK=64, 128-B LDS rows (verified-zero-conflict swizzle), 64 KiB LDS -> 2 blocks/CU.
// Counted-vmcnt(8) pipeline.
__global__ __launch_bounds__(256, 2) void sim_topk_mfma(
    const unsigned short* __restrict__ Qpk, const unsigned short* __restrict__ Cpk,
    unsigned int* __restrict__ part_k) {
  __shared__ __align__(16) unsigned short smem[2][16384];  // [buf][As 8192 | Bs 8192] = 64 KiB

  int tid = threadIdx.x;
  int lane = tid & 63, wid = tid >> 6;
  int wr = wid >> 1, wc = wid & 1;
  // bijective XCD swizzle: a chunk's 8 q-tile blocks land on one XCD (grid 3128 = 8*391)
  int g = (blockIdx.x & 7) * NCHUNK + (blockIdx.x >> 3);
  int chunk = g >> 3, mt = g & 7;
  int m0 = mt * 128;
  int rbase = chunk * CHUNK;
  bool lastChunk = (rbase + CHUNK) > NCORPUS;

  // staging precompute (source-side XOR swizzle of 16B granules within a 128B row)
  int srow = tid >> 3;                          // 0..31
  int scol = (((tid & 7) ^ (srow & 7)) << 3);   // ushort col within 64-wide K-slice

  // fragment ds_read offsets (swizzled), ushort units; row stride 64 ush = 128 B
  int l15 = lane & 15, l4 = lane >> 4, l7 = lane & 7;
  int aoff[2][4], boff[2][4];
#pragma unroll
  for (int kk = 0; kk < 2; ++kk)
#pragma unroll
    for (int q = 0; q < 4; ++q) {
      int sw = (((kk * 4 + l4) ^ l7) << 3);
      aoff[kk][q] = (wr * 64 + q * 16 + l15) * 64 + sw;
      boff[kk][q] = 8192 + (wc * 64 + q * 16 + l15) * 64 + sw;
    }

  float lk[4][NPART];  // per-q-col tagged-float top-4, sorted desc
#pragma unroll
  for (int n = 0; n < 4; ++n)
#pragma unroll
    for (int p = 0; p < NPART; ++p) lk[n][p] = NEGINF;

  f32x4 zero = {0.f, 0.f, 0.f, 0.f};
  f32x4 acc[4][4];
#pragma unroll
  for (int m = 0; m < 4; ++m)
#pragma unroll
    for (int n = 0; n < 4; ++n) acc[m][n] = zero;

  auto stageA = [&](int t, unsigned short* dst) {
    int sub = t >> 3, kt = t & 7;
    int rb = rbase + sub * 128;
    int k0 = kt * 64;
#pragma unroll
    for (int r = 0; r < 4; ++r) {
      int cr = rb + r * 32 + srow;
      if (cr > NCORPUS - 1) cr = NCORPUS - 1;
      gload16(Cpk + (size_t)cr * 512 + k0 + scol, dst + (r * 4 + wid) * 512);
    }
  };
  auto stageB = [&](int t, unsigned short* dst) {
    int kt = t & 7;
    int k0 = kt * 64;
#pragma unroll
    for (int r = 0; r < 4; ++r) {
      int qr = m0 + r * 32 + srow;
      gload16(Qpk + (size_t)qr * 512 + k0 + scol, dst + 8192 + (r * 4 + wid) * 512);
    }
  };

  // prologue: stage tile 0 (8 loads outstanding)
  stageA(0, smem[0]);
  stageB(0, smem[0]);

  for (int t = 0; t < NT; ++t) {
    int t1 = t + 1;
    if (t1 < NT) {
      unsigned short* nb = smem[t1 & 1];
      stageA(t1, nb);
      stageB(t1, nb);
      // wait for stage(t) only; stage(t+1)'s 8 loads stay in flight across the barrier
      asm volatile("s_waitcnt vmcnt(8)" ::: "memory");
    } else {
      asm volatile("s_waitcnt vmcnt(0)" ::: "memory");
    }
    __builtin_amdgcn_s_barrier();   // buf[t] valid for all waves
    const unsigned short* cb = smem[t & 1];
#pragma unroll
    for (int kk = 0; kk < 2; ++kk) {
      bf16x8 a[4], b[4];
#pragma unroll
      for (int m = 0; m < 4; ++m) a[m] = *(const bf16x8*)(cb + aoff[kk][m]);
#pragma unroll
      for (int n = 0; n < 4; ++n) b[n] = *(const bf16x8*)(cb + boff[kk][n]);
#pragma unroll
      for (int m = 0; m < 4; ++m)
#pragma unroll
        for (int n = 0; n < 4; ++n)
          acc[m][n] = __builtin_amdgcn_mfma_f32_16x16x32_bf16(a[m], b[n], acc[m][n], 0, 0, 0);
    }
    if ((t & 7) == 7) {  // sub complete: fold acc into tagged-float top-4 lists
      int sub = t >> 3;
      int cellbase = sub * 128 + wr * 64 + l4 * 4;
      int rb2 = rbase + cellbase;
      int tagbase = (CHUNK - 1) - cellbase;
      if (lastChunk) fold_sub<true>(acc, lk, tagbase, rb2);
      else fold_sub<false>(acc, lk, tagbase, rb2);
#pragma unroll
      for (int m = 0; m < 4; ++m)
#pragma unroll
        for (int n = 0; n < 4; ++n) acc[m][n] = zero;
    }
    __builtin_amdgcn_s_barrier();   // all reads of buf[t] done before stage(t+2) overwrites it
  }

  // ---- block-end merge: per q-col partial lists -> chunk top-4 ----
  // within-wave: merge across l4 groups (xor 16, then 32)
#pragma unroll
  for (int rnd = 0; rnd < 2; ++rnd) {
    int msk = 16 << rnd;
#pragma unroll
    for (int n = 0; n < 4; ++n) {
      float ov[NPART];
#pragma unroll
      for (int p = 0; p < NPART; ++p) ov[p] = __shfl_xor(lk[n][p], msk, 64);
      pmerge4f(lk[n], ov);
    }
  }
  // cross-wave (wr=1 -> LDS -> wr=0)
  float* fb = (float*)&smem[0][0];  // [128][4] tagged floats (2 KB)
  if (wr == 1 && l4 == 0) {
#pragma unroll
    for (int n = 0; n < 4; ++n) {
      int col = wc * 64 + n * 16 + l15;
#pragma unroll
      for (int p = 0; p < NPART; ++p) fb[col * 4 + p] = lk[n][p];
    }
  }
  __syncthreads();
  if (wr == 0 && l4 == 0) {
#pragma unroll
    for (int n = 0; n < 4; ++n) {
      int col = wc * 64 + n * 16 + l15;
      float ov[NPART];
#pragma unroll
      for (int p = 0; p < NPART; ++p) ov[p] = fb[col * 4 + p];
      pmerge4f(lk[n], ov);
      size_t base = ((size_t)(m0 + col) * NCHUNK + chunk) * NPART;
#pragma unroll
      for (int p = 0; p < NPART; ++p) {
        unsigned bits = __float_as_uint(lk[n][p]);
        unsigned tag = bits & 0x3FFu;
        unsigned flip = bits ^ ((unsigned)((int)bits >> 31) | 0x80000000u);
        part_k[base + p] = (flip & 0xFFFFFC00u) | tag;  // 22-bit value | 10-bit comp row
      }
    }
  }
}

// ---------------- merged: merge+refine (blocks 0..255) | tcenc+prop (256..1279) ----------------
__global__ __launch_bounds__(256, 2) void mr_tp_kernel(
    const unsigned int* __restrict__ part_k,
    const double* __restrict__ q64, const float* __restrict__ corpus,
    float* __restrict__ out_scores, float* __restrict__ out_idxf, int* __restrict__ topidx,
    const float* __restrict__ treatment, const float* __restrict__ conf,
    const float* __restrict__ Wte, const float* __restrict__ bte,
    const float* __restrict__ Wce, const float* __restrict__ bce,
    const float* __restrict__ Wp1, const float* __restrict__ bp1,
    const float* __restrict__ Wp2, const float* __restrict__ bp2,
    float* __restrict__ combined, float* __restrict__ out_prop) {
  __shared__ float cs[64];
  __shared__ float red0[4], red1[4];
  int tid = threadIdx.x;
  if (blockIdx.x < 256) {
    int wv = tid >> 6, lane = tid & 63;
    int row = blockIdx.x * 4 + wv;
    if (row >= BROWS) return;

    unsigned tk[16]; int tm[16];
#pragma unroll
    for (int p = 0; p < 16; ++p) { tk[p] = 0u; tm[p] = 0; }
    const unsigned* base = part_k + (size_t)row * (NCHUNK * NPART);
    for (int e = lane; e < NCHUNK * NPART; e += 64) {  // coalesced
      unsigned k = base[e];
      if (k > tk[15]) {
        unsigned kv = k; int mv = e;
#pragma unroll
        for (int p = 0; p < 16; ++p) {
          bool gt = kv > tk[p];
          unsigned ts = tk[p]; int ti = tm[p];
          tk[p] = gt ? kv : ts; tm[p] = gt ? mv : ti;
          kv = gt ? ts : kv;    mv = gt ? ti : mv;
        }
      }
    }
    // exact tree merge across 64 lanes (key + meta pairs)
#pragma unroll
    for (int r = 0; r < 6; ++r) {
      unsigned ov[16]; int om[16];
#pragma unroll
      for (int p = 0; p < 16; ++p) {
        ov[p] = __shfl_xor(tk[p], 1 << r, 64);
        om[p] = __shfl_xor(tm[p], 1 << r, 64);
      }
      unsigned cv[16]; int cm[16];
#pragma unroll
      for (int i = 0; i < 16; ++i) {
        bool t = tk[i] >= ov[15 - i];
        cv[i] = t ? tk[i] : ov[15 - i];
        cm[i] = t ? tm[i] : om[15 - i];
      }
#pragma unroll
      for (int s = 8; s >= 1; s >>= 1)
#pragma unroll
        for (int bb = 0; bb < 16; bb += 2 * s)
#pragma unroll
          for (int o = 0; o < s; ++o) {
            int x = bb + o, y = bb + o + s;
            bool t = cv[x] >= cv[y];
            unsigned hv = t ? cv[x] : cv[y]; unsigned lv = t ? cv[y] : cv[x];
            int hm = t ? cm[x] : cm[y];      int lm = t ? cm[y] : cm[x];
            cv[x] = hv; cm[x] = hm; cv[y] = lv; cm[y] = lm;
          }
#pragma unroll
      for (int i = 0; i < 16; ++i) { tk[i] = cv[i]; tm[i] = cm[i]; }
    }
    int cidx[16];
#pragma unroll
    for (int c = 0; c < 16; ++c) {
      int ic = ((tm[c] >> 2) << 9) + (CHUNK - 1) - (int)(tk[c] & 0x3FFu);
      if (ic > NCORPUS - 1) ic = NCORPUS - 1;
      if (ic < 0) ic = 0;
      cidx[c] = ic;
    }
    // refine all 16 candidates in f64 (wave-parallel dot)
    double qv[8];
    const double* qrow = q64 + (size_t)row * 512;
#pragma unroll
    for (int t = 0; t < 8; ++t) qv[t] = qrow[lane * 8 + t];
    double rs[16];
#pragma unroll
    for (int c = 0; c < 16; ++c) {
      const float* crow = corpus + (size_t)cidx[c] * 512 + lane * 8;
      double qd = 0.0, cd = 0.0;
#pragma unroll
      for (int t = 0; t < 8; ++t) {
        double x = (double)crow[t];
        cd += x * x;
        qd += qv[t] * x;
      }
      qd = wave_sum_f64(qd);
      cd = wave_sum_f64(cd);
      rs[c] = qd / fmax(sqrt(cd), 1e-12);
    }
    if (lane == 0) {
      for (int o = 0; o < TOPK; ++o) {
        double bsc = -1e300;
        int bid2 = 0x7fffffff, bc = -1;
#pragma unroll
        for (int c = 0; c < 16; ++c) {
          bool better = (rs[c] > bsc) || (rs[c] == bsc && cidx[c] < bid2);
          if (better) { bsc = rs[c]; bid2 = cidx[c]; bc = c; }
        }
        out_scores[row * 8 + o] = (float)bsc;
        out_idxf[row * 8 + o] = (float)bid2;
        topidx[row * 8 + o] = bid2;
#pragma unroll
        for (int c = 0; c < 16; ++c)
          if (c == bc) rs[c] = -1e300;
      }
    }
  } else {
    int b = blockIdx.x - 256;
    if (tid < 64) cs[tid] = conf[b * 64 + tid];
    __syncthreads();
    float t0 = treatment[b * 2], t1 = treatment[b * 2 + 1];
    float l0 = 0.f, l1 = 0.f;
#pragma unroll
    for (int rep = 0; rep < 2; ++rep) {
      int h = tid + rep * 256;
      float te = fmaf(t0, Wte[h], fmaf(t1, Wte[512 + h], bte[h]));
      combined[(size_t)b * 1536 + h] = te;
      float ce = bce[h];
      float pv = bp1[h];
      for (int k = 0; k < 64; ++k) {
        float c = cs[k];
        ce = fmaf(c, Wce[k * 512 + h], ce);
        pv = fmaf(c, Wp1[k * 512 + h], pv);
      }
      combined[(size_t)b * 1536 + 512 + h] = ce;
      pv = fmaxf(pv, 0.f);
      l0 = fmaf(pv, Wp2[h * 2], l0);
      l1 = fmaf(pv, Wp2[h * 2 + 1], l1);
    }
    l0 = wave_sum_f32(l0);
    l1 = wave_sum_f32(l1);
    int wv = tid >> 6, lane = tid & 63;
    if (lane == 0) { red0[wv] = l0; red1[wv] = l1; }
    __syncthreads();
    if (tid == 0) {
      float a = red0[0] + red0[1] + red0[2] + red0[3] + bp2[0];
      float c2 = red1[0] + red1[1] + red1[2] + red1[3] + bp2[1];
      float m = fmaxf(a, c2);
      float e0 = expf(a - m), e1 = expf(c2 - m);
      float inv = 1.f / (e0 + e1);
      out_prop[b * 2] = e0 * inv;
      out_prop[b * 2 + 1] = e1 * inv;
    }
  }
}

// ---------------- generic 16x64 tiled GEMM, single-barrier dbuf (opt. gather-A, opt. relu) ----------------
template <bool GATHER, bool RELU>
__global__ __launch_bounds__(256, 2) void gemm_k_kernel(
    const float* __restrict__ A, int lda, const float* __restrict__ W, int ldw,
    const float* __restrict__ bias, float* __restrict__ C, int ldc, int K,
    const int* __restrict__ gidx, const float* __restrict__ corpus) {
  __shared__ float As[2][32 * 17];   // [kk][row] transposed, pitch 17
  __shared__ float Bs[2][32 * 68];
  __shared__ int gi[128];
  int tid = threadIdx.x;
  int m0 = blockIdx.y * 16, n0 = blockIdx.x * 64;
  int tr = tid >> 4, tc = tid & 15;   // output: row tr (0..15), col group tc
  int bn = (tid & 15) * 4, bk = tid >> 4;
  if (GATHER) {
    if (tid < 128) gi[tid] = gidx[m0 * 8 + tid];
    __syncthreads();
  }
  auto stage = [&](int kt, int buf) {
    int k0 = kt * 32;
    if (tid < 128) {
      int row = tid & 15, f4 = tid >> 4;  // f4 0..7
      int kk = k0 + f4 * 4;
      const float* src;
      if (GATHER) {
        int r = gi[row * 8 + (kk >> 9)];
        src = corpus + (size_t)r * 512 + (kk & 511);
      } else {
        src = A + (size_t)(m0 + row) * lda + kk;
      }
      float4 v = *(const float4*)src;
      float* d = As[buf] + (f4 * 4) * 17 + row;
      d[0] = v.x; d[17] = v.y; d[34] = v.z; d[51] = v.w;
    }
#pragma unroll
    for (int r = 0; r < 2; ++r) {
      int kk = bk + r * 16;
      float4 v = *(const float4*)(W + (size_t)(k0 + kk) * ldw + n0 + bn);
      *(float4*)(Bs[buf] + kk * 68 + bn) = v;
    }
  };
  float acc[4] = {0.f, 0.f, 0.f, 0.f};
  int nk = K >> 5;
  stage(0, 0);
  __syncthreads();
  for (int kt = 0; kt < nk; ++kt) {
    int cur = kt & 1;
    if (kt + 1 < nk) stage(kt + 1, cur ^ 1);
    const float* as = As[cur];
    const float* bs = Bs[cur];
#pragma unroll
    for (int k = 0; k < 32; ++k) {
      float a0 = as[k * 17 + tr];
      float4 b4 = *(const float4*)(bs + k * 68 + tc * 4);
      acc[0] = fmaf(a0, b4.x, acc[0]);
      acc[1] = fmaf(a0, b4.y, acc[1]);
      acc[2] = fmaf(a0, b4.z, acc[2]);
      acc[3] = fmaf(a0, b4.w, acc[3]);
    }
    __syncthreads();
  }
  int m = m0 + tr;
#pragma unroll
  for (int j = 0; j < 4; ++j) {
    int n = n0 + tc * 4 + j;
    float v = acc[j] + bias[n];
    if (RELU) v = fmaxf(v, 0.f);
    C[(size_t)m * ldc + n] = v;
  }
}

// ---------------- outcome head (N=1) ----------------
__global__ void outcome_kernel(const float* __restrict__ h2, const float* __restrict__ Wo3,
                               const float* __restrict__ bo3, float* __restrict__ out) {
  int wv = threadIdx.x >> 6, lane = threadIdx.x & 63;
  int row = blockIdx.x * 4 + wv;
  if (row >= BROWS) return;
  float4 a = ((const float4*)(h2 + (size_t)row * 256))[lane];
  float4 w = ((const float4*)Wo3)[lane];
  float s = a.x * w.x + a.y * w.y + a.z * w.z + a.w * w.w;
  s = wave_sum_f32(s);
  if (lane == 0) out[row] = s + bo3[0];
}

extern "C" void kernel_launch(void* const* d_in, const int* in_sizes, int n_in,
                              void* d_out, int out_size, void* d_ws, size_t ws_size,
                              hipStream_t stream) {
  const float* treatment = (const float*)d_in[0];
  const float* conf = (const float*)d_in[1];
  const float* patient = (const float*)d_in[2];
  const float* corpus = (const float*)d_in[3];
  const float* Wpe = (const float*)d_in[4];
  const float* bpe = (const float*)d_in[5];
  const float* Wte = (const float*)d_in[6];
  const float* bte = (const float*)d_in[7];
  const float* Wce = (const float*)d_in[8];
  const float* bce = (const float*)d_in[9];
  const float* Wre = (const float*)d_in[10];
  const float* bre = (const float*)d_in[11];
  const float* Wo1 = (const float*)d_in[12];
  const float* bo1 = (const float*)d_in[13];
  const float* Wo2 = (const float*)d_in[14];
  const float* bo2 = (const float*)d_in[15];
  const float* Wo3 = (const float*)d_in[16];
  const float* bo3 = (const float*)d_in[17];
  const float* Wp1 = (const float*)d_in[18];
  const float* bp1 = (const float*)d_in[19];
  const float* Wp2 = (const float*)d_in[20];
  const float* bp2 = (const float*)d_in[21];

  float* out = (float*)d_out;
  float* out_outcome = out;                       // [1024]
  float* out_scores = out + 1024;                 // [1024*8]
  float* out_idxf = out + 1024 + 8192;            // [1024*8] (ints as float)
  float* out_prop = out + 1024 + 8192 + 8192;     // [1024*2]

  char* ws = (char*)d_ws;
  size_t off = 0;
  auto carve = [&](size_t bytes) {
    void* p = ws + off;
    off = (off + bytes + 255) & ~(size_t)255;
    return p;
  };
  double* q64 = (double*)carve((size_t)1024 * 512 * 8);
  unsigned short* Qpk = (unsigned short*)carve((size_t)1024 * 512 * 2);
  unsigned short* Cpk = (unsigned short*)carve((size_t)NCORPUS * 512 * 2);
  unsigned int* part_k = (unsigned int*)carve((size_t)1024 * NCHUNK * NPART * 4);
  int* topidx = (int*)carve((size_t)1024 * 8 * 4);
  float* combined = (float*)carve((size_t)1024 * 1536 * 4);
  float* h1 = (float*)carve((size_t)1024 * 512 * 4);
  float* h2 = (float*)carve((size_t)1024 * 256 * 4);

  prep_kernel<<<dim3(51024), dim3(256), 0, stream>>>(corpus, Cpk, patient, Wpe, bpe, q64, Qpk);
  sim_topk_mfma<<<dim3(8 * NCHUNK), dim3(256), 0, stream>>>(Qpk, Cpk, part_k);
  mr_tp_kernel<<<dim3(1280), dim3(256), 0, stream>>>(part_k, q64, corpus,
                                                     out_scores, out_idxf, topidx,
                                                     treatment, conf, Wte, bte, Wce, bce,
                                                     Wp1, bp1, Wp2, bp2, combined, out_prop);
  gemm_k_kernel<true, false><<<dim3(8, 64), dim3(256), 0, stream>>>(
      (const float*)nullptr, 0, Wre, 512, bre, combined + 1024, 1536, 4096, topidx, corpus);
  gemm_k_kernel<false, true><<<dim3(8, 64), dim3(256), 0, stream>>>(
      combined, 1536, Wo1, 512, bo1, h1, 512, 1536, (const int*)nullptr, (const float*)nullptr);
  gemm_k_kernel<false, true><<<dim3(4, 64), dim3(256), 0, stream>>>(
      h1, 512, Wo2, 256, bo2, h2, 256, 512, (const int*)nullptr, (const float*)nullptr);
  outcome_kernel<<<dim3(256), dim3(256), 0, stream>>>(h2, Wo3, bo3, out_outcome);
}